// Round 21
// baseline (158.604 us; speedup 1.0000x reference)
//
#include <hip/hip_runtime.h>

#define DIMC   512
#define NHEADS 8
#define HDIM   64
#define DD     6
#define HHH    48
#define WWW    96
#define NPOS   (DD * HHH * WWW)   // 27648

typedef unsigned short u16;
typedef __attribute__((ext_vector_type(8))) short bf16x8;
typedef __attribute__((ext_vector_type(4))) float f32x4;

static __device__ __forceinline__ float b2f(u16 u) {
    return __builtin_bit_cast(float, (unsigned)u << 16);
}
static __device__ __forceinline__ u16 f2b(float f) {
    unsigned x = __builtin_bit_cast(unsigned, f);
    return (u16)((x + 0x7fffu + ((x >> 16) & 1u)) >> 16);
}

static __device__ __forceinline__ void gload_lds16(const void* g, void* l) {
    __builtin_amdgcn_global_load_lds((const __attribute__((address_space(1))) void*)g,
                                     (__attribute__((address_space(3))) void*)l, 16, 0, 0);
}

// ---------------------------------------------------------------------------
// fused converts (known-good R17)
// ---------------------------------------------------------------------------
__global__ __launch_bounds__(256) void cvt_all(
    const float* __restrict__ x, const float* __restrict__ w_qkv,
    const float* __restrict__ w_proj, u16* __restrict__ xb,
    u16* __restrict__ wqkvT, u16* __restrict__ wprojT)
{
    const int bid = blockIdx.x;
    const int tid = threadIdx.x;
    if (bid < 13824) {
        const int i = bid * 256 + tid;
        float4 v = reinterpret_cast<const float4*>(x)[i];
        ushort4 o = { f2b(v.x), f2b(v.y), f2b(v.z), f2b(v.w) };
        reinterpret_cast<ushort4*>(xb)[i] = o;
    } else if (bid < 13824 + 3072) {
        const int id = (bid - 13824) * 256 + tid;
        const int nn = id >> 9, kk = id & 511;
        wqkvT[id] = f2b(w_qkv[(size_t)kk * 1536 + nn]);
    } else {
        const int id = (bid - 16896) * 256 + tid;
        const int nn = id >> 9, kk = id & 511;
        wprojT[id] = f2b(w_proj[(size_t)kk * 512 + nn]);
    }
}

// ---------------------------------------------------------------------------
// bf16 MFMA GEMM — R21: 256x128 tile, BK=32, LDS DOUBLE-BUFFER (stage-ahead).
// Step k: stage tile k+1 into buf^1 FIRST, then ds_read+MFMA from buf, then
// ONE __syncthreads(). The barrier's mandatory vmcnt(0) drain lands after the
// compute phase, so the staged loads have ~400-600 cyc to return (R17/R20
// order was stage -> barrier -> compute: full L2 latency exposed per step).
// Race-free by barrier separation: reads of buf drained (lgkmcnt) before the
// previous barrier; writes to buf^1 issue after it; no buffer is read and
// written in the same interval (the R10 lesson).
// MFMA k-order identical to BK=64 two-half form -> bit-identical output.
// Swizzle: R8's measured-0-conflict involution for 32-elem rows
// (src chunk (t&3)^((t>>3)&3); frag-read chunk g^((c>>1)&3)).
// LDS 2 x 24 KB = 48 KB (unchanged). cmode==1 pre-scales q by log2(e)/64.
// ---------------------------------------------------------------------------
__global__ __launch_bounds__(512) void gemm_bf16_mfma(
    const u16* __restrict__ A, int lda,
    const u16* __restrict__ B, int ldb,
    const float* __restrict__ bias, int Kp,
    void* __restrict__ Cout, int ldc, int cmode, int nx)
{
    __shared__ u16 As[2][256 * 32];
    __shared__ u16 Bs[2][128 * 32];

    const int tid = threadIdx.x;
    const int l   = tid & 63;
    const int w   = tid >> 6;
    const int wr  = w >> 1;        // 0..3 (M)
    const int wc  = w & 1;         // 0..1 (N)

    const int cpx = gridDim.x >> 3;
    const int idp = (blockIdx.x & 7) * cpx + (blockIdx.x >> 3);
    const int by  = idp / nx;
    const int bx  = idp - by * nx;
    const int m0  = by * 256;
    const int n0  = bx * 128;

    // staging: thread t -> row t>>2 (0..127), phys chunk t&3; source column
    // carries the inverse swizzle (t&3)^((t>>3)&3). Lane-linear LDS dest:
    // offset = w*512 + l*8 elems (wave-uniform base + lane*16B).
    const int srow = tid >> 2;                        // 0..127
    const int schk = ((tid & 3) ^ ((tid >> 3) & 3)) * 8;

    const u16* ga = A + (size_t)(m0 + srow) * lda + schk;   // rows 0..127
    const u16* gb = B + (size_t)(n0 + srow) * ldb + schk;   // rows 0..127
    const size_t a128 = (size_t)128 * lda;                  // A rows 128..255
    const int sdst = w * 512 + l * 8;                       // elems

    f32x4 acc[4][4];
#pragma unroll
    for (int i = 0; i < 4; i++)
#pragma unroll
        for (int j = 0; j < 4; j++) acc[i][j] = (f32x4)0.0f;

    const int c  = l & 15;
    const int g  = l >> 4;
    const int lk = (g ^ ((c >> 1) & 3)) * 8;   // frag-read chunk (0-conflict, R8)

#define STG(buf, kt) do {                                                      \
    const size_t ko = (size_t)(kt) * 32;                                       \
    gload_lds16(ga + ko,        &As[buf][sdst]);                               \
    gload_lds16(ga + a128 + ko, &As[buf][128 * 32 + sdst]);                    \
    gload_lds16(gb + ko,        &Bs[buf][sdst]);                               \
} while (0)

    const int nsteps = Kp >> 5;   // 16 for K=512

    STG(0, 0);
    __syncthreads();

#pragma unroll 1
    for (int k = 0; k < nsteps; ++k) {
        const int cur = k & 1;
        if (k + 1 < nsteps) STG(cur ^ 1, k + 1);   // stage ahead (issue only)

        bf16x8 af[4], bfr[4];
#pragma unroll
        for (int f = 0; f < 4; f++) {
            af[f]  = *reinterpret_cast<const bf16x8*>(&As[cur][(wr * 64 + f * 16 + c) * 32 + lk]);
            bfr[f] = *reinterpret_cast<const bf16x8*>(&Bs[cur][(wc * 64 + f * 16 + c) * 32 + lk]);
        }
#pragma unroll
        for (int i = 0; i < 4; i++)
#pragma unroll
            for (int j = 0; j < 4; j++)
                acc[i][j] = __builtin_amdgcn_mfma_f32_16x16x32_bf16(af[i], bfr[j], acc[i][j], 0, 0, 0);

        __syncthreads();   // drain lands AFTER compute: staged loads had cover
    }
#undef STG

#pragma unroll
    for (int i = 0; i < 4; i++) {
        const int mb = m0 + wr * 64 + i * 16 + g * 4;
#pragma unroll
        for (int j = 0; j < 4; j++) {
            const int n = n0 + wc * 64 + j * 16 + c;
            const float bv = bias[n];
            const float scn = (cmode && n < 512) ? 0.022542110f : 1.0f;  // log2(e)/64
#pragma unroll
            for (int r = 0; r < 4; r++) {
                const float v = (acc[i][j][r] + bv) * scn;
                if (cmode) reinterpret_cast<u16*>(Cout)[(size_t)(mb + r) * ldc + n] = f2b(v);
                else       reinterpret_cast<float*>(Cout)[(size_t)(mb + r) * ldc + n] = v;
            }
        }
    }
}

// ---------------------------------------------------------------------------
// MFMA neighborhood attention — R20 2x4x4 configuration (known-good).
// ---------------------------------------------------------------------------
__global__ __launch_bounds__(512, 4) void na3d_mfma(
    const u16* __restrict__ qkv, u16* __restrict__ attnc)
{
    __shared__ int   rowoff[256];
    __shared__ int   dlt[16];
    __shared__ u16   Vt[NHEADS][64][36];
    __shared__ float ssum_lds[NHEADS][2][16];

    const int bid = blockIdx.x;
    const int x   = bid & 7;
    const int u   = bid >> 3;
    const int twl = u / 36;
    const int r2  = u - twl * 36;
    const int d0  = r2 / 12;
    const int thp = r2 - d0 * 12;
    const int h0  = thp * 4;
    const int w0  = (3 * x + twl) * 4;
    const int sdu = min(max(2 * d0 - 1, 0), DD - 4);
    const int shb = min(max(h0 - 2, 0), HHH - 5);
    const int swb = min(max(w0 - 2, 0), WWW - 5);
    const int ddlt0 = min(max(2 * d0 - 1, 0), DD - 3) - sdu;
    const int ddlt1 = min(max(2 * d0, 0), DD - 3) - sdu;

    const int tid = threadIdx.x;
    if (tid < 256) {
        const int dd = tid >> 6, hh = (tid >> 3) & 7, wu = tid & 7;
        const int row = (sdu + dd) * (HHH * WWW)
                      + min(shb + hh, HHH - 1) * WWW + min(swb + wu, WWW - 1);
        rowoff[tid] = row * 1536;
    }
    if (tid < 16) {
        const int ph = h0 + (tid >> 2), pw = w0 + (tid & 3);
        const int dh = min(max(ph - 2, 0), HHH - 5) - shb;
        const int dw = min(max(pw - 2, 0), WWW - 5) - swb;
        dlt[tid] = (dh << 4) | dw;
    }
    __syncthreads();

    const int head = tid >> 6;
    const int l    = tid & 63;
    const int g    = l >> 4;
    const int c    = l & 15;

    const int qbase = (h0 + (c >> 2)) * WWW + (w0 + (c & 3));
    const u16* qrow0 = qkv + (size_t)((2 * d0)     * (HHH * WWW) + qbase) * 1536 + head * HDIM;
    const u16* qrow1 = qkv + (size_t)((2 * d0 + 1) * (HHH * WWW) + qbase) * 1536 + head * HDIM;
    const bf16x8 qlo0 = *reinterpret_cast<const bf16x8*>(qrow0 + 8 * g);
    const bf16x8 qhi0 = *reinterpret_cast<const bf16x8*>(qrow0 + 32 + 8 * g);
    const bf16x8 qlo1 = *reinterpret_cast<const bf16x8*>(qrow1 + 8 * g);
    const bf16x8 qhi1 = *reinterpret_cast<const bf16x8*>(qrow1 + 32 + 8 * g);
    const int dparts = dlt[c];
    const int dh = dparts >> 4, dw = dparts & 15;

    f32x4 oacc0[4], oacc1[4];
#pragma unroll
    for (int j = 0; j < 4; j++) { oacc0[j] = (f32x4)0.0f; oacc1[j] = (f32x4)0.0f; }
    float ssum0 = 0.0f, ssum1 = 0.0f;

#pragma unroll 1
    for (int s = 0; s < 8; ++s) {
        {
            const int npair = l >> 2;
            const int chq   = l & 3;
#pragma unroll
            for (int rr = 0; rr < 2; ++rr) {
                const int ch8 = 8 * chq + 32 * rr;
                const int2 rp = *reinterpret_cast<const int2*>(&rowoff[s * 32 + 2 * npair]);
                const ushort4* pa = reinterpret_cast<const ushort4*>(qkv + rp.x + 1024 + head * HDIM + ch8);
                const ushort4* pb = reinterpret_cast<const ushort4*>(qkv + rp.y + 1024 + head * HDIM + ch8);
                ushort4 va0 = pa[0], va1 = pa[1];
                ushort4 vb0 = pb[0], vb1 = pb[1];
                const u16* va = reinterpret_cast<const u16*>(&va0);
                const u16* vb = reinterpret_cast<const u16*>(&vb0);
#pragma unroll
                for (int e = 0; e < 4; ++e) {
                    unsigned dwo = (unsigned)va[e] | ((unsigned)vb[e] << 16);
                    *reinterpret_cast<unsigned*>(&Vt[head][ch8 + e][2 * npair]) = dwo;
                }
                const u16* va2 = reinterpret_cast<const u16*>(&va1);
                const u16* vb2 = reinterpret_cast<const u16*>(&vb1);
#pragma unroll
                for (int e = 0; e < 4; ++e) {
                    unsigned dwo = (unsigned)va2[e] | ((unsigned)vb2[e] << 16);
                    *reinterpret_cast<unsigned*>(&Vt[head][ch8 + 4 + e][2 * npair]) = dwo;
                }
            }
        }

        f32x4 sf00 = (f32x4)0.0f, sf01 = (f32x4)0.0f;
        f32x4 sf10 = (f32x4)0.0f, sf11 = (f32x4)0.0f;
        {
            const int ro = rowoff[s * 32 + c];
            const u16* kr = qkv + ro + 512 + head * HDIM;
            const bf16x8 klo = *reinterpret_cast<const bf16x8*>(kr + 8 * g);
            const bf16x8 khi = *reinterpret_cast<const bf16x8*>(kr + 32 + 8 * g);
            sf00 = __builtin_amdgcn_mfma_f32_16x16x32_bf16(klo, qlo0, sf00, 0, 0, 0);
            sf00 = __builtin_amdgcn_mfma_f32_16x16x32_bf16(khi, qhi0, sf00, 0, 0, 0);
            sf01 = __builtin_amdgcn_mfma_f32_16x16x32_bf16(klo, qlo1, sf01, 0, 0, 0);
            sf01 = __builtin_amdgcn_mfma_f32_16x16x32_bf16(khi, qhi1, sf01, 0, 0, 0);
        }
        {
            const int ro = rowoff[s * 32 + 16 + c];
            const u16* kr = qkv + ro + 512 + head * HDIM;
            const bf16x8 klo = *reinterpret_cast<const bf16x8*>(kr + 8 * g);
            const bf16x8 khi = *reinterpret_cast<const bf16x8*>(kr + 32 + 8 * g);
            sf10 = __builtin_amdgcn_mfma_f32_16x16x32_bf16(klo, qlo0, sf10, 0, 0, 0);
            sf10 = __builtin_amdgcn_mfma_f32_16x16x32_bf16(khi, qhi0, sf10, 0, 0, 0);
            sf11 = __builtin_amdgcn_mfma_f32_16x16x32_bf16(klo, qlo1, sf11, 0, 0, 0);
            sf11 = __builtin_amdgcn_mfma_f32_16x16x32_bf16(khi, qhi1, sf11, 0, 0, 0);
        }

        const int sbA  = s * 32 + 4 * g;
        const int sbB  = sbA + 16;
        const int ddA  = sbA >> 6, hhA = (sbA >> 3) & 7, wuA = sbA & 7;
        const int ddB  = sbB >> 6, hhB = (sbB >> 3) & 7, wuB = sbB & 7;
        const bool hvA = ((unsigned)(hhA - dh) < 5u);
        const bool hvB = ((unsigned)(hhB - dh) < 5u);

        unsigned pA0, pB0, pC0, pD0, pA1, pB1, pC1, pD1;
#define EXPPACK(sf, dvA_, pX, pY, SSUM, hv_, wu_) do {                          \
    const bool v_ = (dvA_) && (hv_);                                            \
    const float e0 = (v_ && (unsigned)((wu_) + 0 - dw) < 5u) ? exp2f((sf)[0]) : 0.0f; \
    const float e1 = (v_ && (unsigned)((wu_) + 1 - dw) < 5u) ? exp2f((sf)[1]) : 0.0f; \
    const float e2 = (v_ && (unsigned)((wu_) + 2 - dw) < 5u) ? exp2f((sf)[2]) : 0.0f; \
    const float e3 = (v_ && (unsigned)((wu_) + 3 - dw) < 5u) ? exp2f((sf)[3]) : 0.0f; \
    SSUM += e0 + e1 + e2 + e3;                                                  \
    pX = (unsigned)f2b(e0) | ((unsigned)f2b(e1) << 16);                         \
    pY = (unsigned)f2b(e2) | ((unsigned)f2b(e3) << 16);                         \
} while (0)

        EXPPACK(sf00, ((unsigned)(ddA - ddlt0) < 3u), pA0, pB0, ssum0, hvA, wuA);
        EXPPACK(sf10, ((unsigned)(ddB - ddlt0) < 3u), pC0, pD0, ssum0, hvB, wuB);
        EXPPACK(sf01, ((unsigned)(ddA - ddlt1) < 3u), pA1, pB1, ssum1, hvA, wuA);
        EXPPACK(sf11, ((unsigned)(ddB - ddlt1) < 3u), pC1, pD1, ssum1, hvB, wuB);
#undef EXPPACK

        asm volatile("v_permlane32_swap_b32 %0, %1" : "+v"(pA0), "+v"(pC0));
        asm volatile("v_permlane32_swap_b32 %0, %1" : "+v"(pB0), "+v"(pD0));
        asm volatile("v_permlane16_swap_b32 %0, %1" : "+v"(pA0), "+v"(pC0));
        asm volatile("v_permlane16_swap_b32 %0, %1" : "+v"(pB0), "+v"(pD0));
        asm volatile("v_permlane32_swap_b32 %0, %1" : "+v"(pA1), "+v"(pC1));
        asm volatile("v_permlane32_swap_b32 %0, %1" : "+v"(pB1), "+v"(pD1));
        asm volatile("v_permlane16_swap_b32 %0, %1" : "+v"(pA1), "+v"(pC1));
        asm volatile("v_permlane16_swap_b32 %0, %1" : "+v"(pB1), "+v"(pD1));

        {
            const bf16x8 pf0 = __builtin_bit_cast(bf16x8,
                make_int4((int)pA0, (int)pB0, (int)pC0, (int)pD0));
            const bf16x8 pf1 = __builtin_bit_cast(bf16x8,
                make_int4((int)pA1, (int)pB1, (int)pC1, (int)pD1));
#pragma unroll
            for (int j = 0; j < 4; ++j) {
                const uint2 v01 = *reinterpret_cast<const uint2*>(&Vt[head][16 * j + c][8 * g]);
                const uint2 v23 = *reinterpret_cast<const uint2*>(&Vt[head][16 * j + c][8 * g + 4]);
                const bf16x8 vfrag = __builtin_bit_cast(bf16x8,
                    make_int4((int)v01.x, (int)v01.y, (int)v23.x, (int)v23.y));
                oacc0[j] = __builtin_amdgcn_mfma_f32_16x16x32_bf16(pf0, vfrag, oacc0[j], 0, 0, 0);
                oacc1[j] = __builtin_amdgcn_mfma_f32_16x16x32_bf16(pf1, vfrag, oacc1[j], 0, 0, 0);
            }
        }
    }

    ssum0 += __shfl_xor(ssum0, 16);
    ssum0 += __shfl_xor(ssum0, 32);
    ssum1 += __shfl_xor(ssum1, 16);
    ssum1 += __shfl_xor(ssum1, 32);
    if (l < 16) {
        ssum_lds[head][0][c] = ssum0;
        ssum_lds[head][1][c] = ssum1;
    }
    const f32x4 sums40 = *reinterpret_cast<const f32x4*>(&ssum_lds[head][0][4 * g]);
    const f32x4 sums41 = *reinterpret_cast<const f32x4*>(&ssum_lds[head][1][4 * g]);

    const int obase = (h0 + g) * WWW + w0;
    const int orow0 = (2 * d0)     * (HHH * WWW) + obase;
    const int orow1 = (2 * d0 + 1) * (HHH * WWW) + obase;
#pragma unroll
    for (int r = 0; r < 4; ++r) {
        const float inv0 = 1.0f / sums40[r];
        const float inv1 = 1.0f / sums41[r];
        u16* base0 = attnc + (size_t)(orow0 + r) * 512 + head * HDIM;
        u16* base1 = attnc + (size_t)(orow1 + r) * 512 + head * HDIM;
#pragma unroll
        for (int j = 0; j < 4; ++j) {
            base0[16 * j + c] = f2b(oacc0[j][r] * inv0);
            base1[16 * j + c] = f2b(oacc1[j][r] * inv1);
        }
    }
}

// ---------------------------------------------------------------------------
extern "C" void kernel_launch(void* const* d_in, const int* in_sizes, int n_in,
                              void* d_out, int out_size, void* d_ws, size_t ws_size,
                              hipStream_t stream)
{
    const float* x      = (const float*)d_in[0];
    const float* w_qkv  = (const float*)d_in[1];
    const float* b_qkv  = (const float*)d_in[2];
    const float* w_proj = (const float*)d_in[3];
    const float* b_proj = (const float*)d_in[4];
    float* out = (float*)d_out;

    u16* qkvb   = (u16*)d_ws;                         // [27648][1536]
    u16* attnc  = qkvb  + (size_t)NPOS * 1536;        // [27648][512] bf16
    u16* xb     = attnc + (size_t)NPOS * 512;         // [27648][512]
    u16* wqkvT  = xb    + (size_t)NPOS * 512;         // [1536][512]
    u16* wprojT = wqkvT + (size_t)1536 * 512;         // [512][512]

    // 0) all converts in one launch
    cvt_all<<<17920, 256, 0, stream>>>(x, w_qkv, w_proj, xb, wqkvT, wprojT);

    // 1) qkv = x @ w_qkv + b_qkv (q pre-scaled); grid 108*12 = 1296 = 8*162
    gemm_bf16_mfma<<<(NPOS / 256) * (1536 / 128), 512, 0, stream>>>(
        xb, 512, wqkvT, 512, b_qkv, 512, qkvb, 1536, 1, 1536 / 128);

    // 2) attention -> bf16 [NPOS][512]; 864 blocks = 8 x 108 (2x4x4 tiles)
    na3d_mfma<<<NPOS / 32, 512, 0, stream>>>(qkvb, attnc);

    // 3) out = attn @ w_proj + b_proj ; grid 108*4 = 432 = 8*54
    gemm_bf16_mfma<<<(NPOS / 256) * (512 / 128), 512, 0, stream>>>(
        attnc, 512, wprojT, 512, b_proj, 512, out, 512, 0, 512 / 128);
}

// Round 22
// 153.324 us; speedup vs baseline: 1.0344x; 1.0344x over previous
//
#include <hip/hip_runtime.h>

#define DIMC   512
#define NHEADS 8
#define HDIM   64
#define DD     6
#define HHH    48
#define WWW    96
#define NPOS   (DD * HHH * WWW)   // 27648

typedef unsigned short u16;
typedef __attribute__((ext_vector_type(8))) short bf16x8;
typedef __attribute__((ext_vector_type(4))) float f32x4;

static __device__ __forceinline__ float b2f(u16 u) {
    return __builtin_bit_cast(float, (unsigned)u << 16);
}
static __device__ __forceinline__ u16 f2b(float f) {
    unsigned x = __builtin_bit_cast(unsigned, f);
    return (u16)((x + 0x7fffu + ((x >> 16) & 1u)) >> 16);
}

static __device__ __forceinline__ void gload_lds16(const void* g, void* l) {
    __builtin_amdgcn_global_load_lds((const __attribute__((address_space(1))) void*)g,
                                     (__attribute__((address_space(3))) void*)l, 16, 0, 0);
}

// ---------------------------------------------------------------------------
// fused converts (known-good R17)
// ---------------------------------------------------------------------------
__global__ __launch_bounds__(256) void cvt_all(
    const float* __restrict__ x, const float* __restrict__ w_qkv,
    const float* __restrict__ w_proj, u16* __restrict__ xb,
    u16* __restrict__ wqkvT, u16* __restrict__ wprojT)
{
    const int bid = blockIdx.x;
    const int tid = threadIdx.x;
    if (bid < 13824) {
        const int i = bid * 256 + tid;
        float4 v = reinterpret_cast<const float4*>(x)[i];
        ushort4 o = { f2b(v.x), f2b(v.y), f2b(v.z), f2b(v.w) };
        reinterpret_cast<ushort4*>(xb)[i] = o;
    } else if (bid < 13824 + 3072) {
        const int id = (bid - 13824) * 256 + tid;
        const int nn = id >> 9, kk = id & 511;
        wqkvT[id] = f2b(w_qkv[(size_t)kk * 1536 + nn]);
    } else {
        const int id = (bid - 16896) * 256 + tid;
        const int nn = id >> 9, kk = id & 511;
        wprojT[id] = f2b(w_proj[(size_t)kk * 512 + nn]);
    }
}

// ---------------------------------------------------------------------------
// bf16 MFMA GEMM — R20 configuration (known-good): 256x128 tile, BK=64,
// 8 waves (4M x 2N), single-buffer 2-phase. cmode==1 pre-scales q (n<512)
// by log2(e)/64.
// NEGATIVE RESULTS (do not retry): R9/R10 256^2 counted-vmcnt pipeline
// (under-depth stall, then stage-into-live-buffer race); R21 BK=32 dbuf
// stage-ahead (doubling barrier-drain events outweighed latency cover:
// 60.5 -> 67.6 us). Barrier-event count dominates on this structure;
// BK=64 single-buffer is the local optimum.
// ---------------------------------------------------------------------------
__global__ __launch_bounds__(512) void gemm_bf16_mfma(
    const u16* __restrict__ A, int lda,
    const u16* __restrict__ B, int ldb,
    const float* __restrict__ bias, int Kp,
    void* __restrict__ Cout, int ldc, int cmode, int nx)
{
    __shared__ u16 As[256 * 64];
    __shared__ u16 Bs[128 * 64];

    const int tid = threadIdx.x;
    const int l   = tid & 63;
    const int w   = tid >> 6;
    const int wr  = w >> 1;
    const int wc  = w & 1;

    const int cpx = gridDim.x >> 3;
    const int idp = (blockIdx.x & 7) * cpx + (blockIdx.x >> 3);
    const int by  = idp / nx;
    const int bx  = idp - by * nx;
    const int m0  = by * 256;
    const int n0  = bx * 128;

    const int lrow = l >> 3;
    const int swz  = ((l & 7) ^ lrow) * 8;
    const int arow = w * 32 + lrow;
    const int brow = w * 16 + lrow;

    const u16* ga = A + (size_t)(m0 + arow) * lda + swz;
    const u16* gb = B + (size_t)(n0 + brow) * ldb + swz;
    const size_t a8 = (size_t)8 * lda;
    const size_t b8 = (size_t)8 * ldb;
    u16* const la0 = As + w * 2048;
    u16* const lb0 = Bs + w * 1024;

    f32x4 acc[4][4];
#pragma unroll
    for (int i = 0; i < 4; i++)
#pragma unroll
        for (int j = 0; j < 4; j++) acc[i][j] = (f32x4)0.0f;

    const int c   = l & 15;
    const int g   = l >> 4;
    const int lk0 = ((0 * 4 + g) ^ (c & 7)) * 8;
    const int lk1 = ((1 * 4 + g) ^ (c & 7)) * 8;

#pragma unroll 1
    for (int k0 = 0; k0 < Kp; k0 += 64) {
#pragma unroll
        for (int q = 0; q < 4; ++q)
            gload_lds16(ga + q * a8, la0 + q * 512);
#pragma unroll
        for (int q = 0; q < 2; ++q)
            gload_lds16(gb + q * b8, lb0 + q * 512);
        ga += 64; gb += 64;
        __syncthreads();

        {
            bf16x8 af[4], bfr[4];
#pragma unroll
            for (int f = 0; f < 4; f++) {
                af[f]  = *reinterpret_cast<const bf16x8*>(&As[(wr * 64 + f * 16 + c) * 64 + lk0]);
                bfr[f] = *reinterpret_cast<const bf16x8*>(&Bs[(wc * 64 + f * 16 + c) * 64 + lk0]);
            }
#pragma unroll
            for (int i = 0; i < 4; i++)
#pragma unroll
                for (int j = 0; j < 4; j++)
                    acc[i][j] = __builtin_amdgcn_mfma_f32_16x16x32_bf16(af[i], bfr[j], acc[i][j], 0, 0, 0);
        }
        {
            bf16x8 af[4], bfr[4];
#pragma unroll
            for (int f = 0; f < 4; f++) {
                af[f]  = *reinterpret_cast<const bf16x8*>(&As[(wr * 64 + f * 16 + c) * 64 + lk1]);
                bfr[f] = *reinterpret_cast<const bf16x8*>(&Bs[(wc * 64 + f * 16 + c) * 64 + lk1]);
            }
#pragma unroll
            for (int i = 0; i < 4; i++)
#pragma unroll
                for (int j = 0; j < 4; j++)
                    acc[i][j] = __builtin_amdgcn_mfma_f32_16x16x32_bf16(af[i], bfr[j], acc[i][j], 0, 0, 0);
        }
        __syncthreads();
    }

#pragma unroll
    for (int i = 0; i < 4; i++) {
        const int mb = m0 + wr * 64 + i * 16 + g * 4;
#pragma unroll
        for (int j = 0; j < 4; j++) {
            const int n = n0 + wc * 64 + j * 16 + c;
            const float bv = bias[n];
            const float scn = (cmode && n < 512) ? 0.022542110f : 1.0f;  // log2(e)/64
#pragma unroll
            for (int r = 0; r < 4; r++) {
                const float v = (acc[i][j][r] + bv) * scn;
                if (cmode) reinterpret_cast<u16*>(Cout)[(size_t)(mb + r) * ldc + n] = f2b(v);
                else       reinterpret_cast<float*>(Cout)[(size_t)(mb + r) * ldc + n] = v;
            }
        }
    }
}

// ---------------------------------------------------------------------------
// MFMA neighborhood attention — R20 2x4x4 configuration (known-good).
// ---------------------------------------------------------------------------
__global__ __launch_bounds__(512, 4) void na3d_mfma(
    const u16* __restrict__ qkv, u16* __restrict__ attnc)
{
    __shared__ int   rowoff[256];
    __shared__ int   dlt[16];
    __shared__ u16   Vt[NHEADS][64][36];
    __shared__ float ssum_lds[NHEADS][2][16];

    const int bid = blockIdx.x;
    const int x   = bid & 7;
    const int u   = bid >> 3;
    const int twl = u / 36;
    const int r2  = u - twl * 36;
    const int d0  = r2 / 12;
    const int thp = r2 - d0 * 12;
    const int h0  = thp * 4;
    const int w0  = (3 * x + twl) * 4;
    const int sdu = min(max(2 * d0 - 1, 0), DD - 4);
    const int shb = min(max(h0 - 2, 0), HHH - 5);
    const int swb = min(max(w0 - 2, 0), WWW - 5);
    const int ddlt0 = min(max(2 * d0 - 1, 0), DD - 3) - sdu;
    const int ddlt1 = min(max(2 * d0, 0), DD - 3) - sdu;

    const int tid = threadIdx.x;
    if (tid < 256) {
        const int dd = tid >> 6, hh = (tid >> 3) & 7, wu = tid & 7;
        const int row = (sdu + dd) * (HHH * WWW)
                      + min(shb + hh, HHH - 1) * WWW + min(swb + wu, WWW - 1);
        rowoff[tid] = row * 1536;
    }
    if (tid < 16) {
        const int ph = h0 + (tid >> 2), pw = w0 + (tid & 3);
        const int dh = min(max(ph - 2, 0), HHH - 5) - shb;
        const int dw = min(max(pw - 2, 0), WWW - 5) - swb;
        dlt[tid] = (dh << 4) | dw;
    }
    __syncthreads();

    const int head = tid >> 6;
    const int l    = tid & 63;
    const int g    = l >> 4;
    const int c    = l & 15;

    const int qbase = (h0 + (c >> 2)) * WWW + (w0 + (c & 3));
    const u16* qrow0 = qkv + (size_t)((2 * d0)     * (HHH * WWW) + qbase) * 1536 + head * HDIM;
    const u16* qrow1 = qkv + (size_t)((2 * d0 + 1) * (HHH * WWW) + qbase) * 1536 + head * HDIM;
    const bf16x8 qlo0 = *reinterpret_cast<const bf16x8*>(qrow0 + 8 * g);
    const bf16x8 qhi0 = *reinterpret_cast<const bf16x8*>(qrow0 + 32 + 8 * g);
    const bf16x8 qlo1 = *reinterpret_cast<const bf16x8*>(qrow1 + 8 * g);
    const bf16x8 qhi1 = *reinterpret_cast<const bf16x8*>(qrow1 + 32 + 8 * g);
    const int dparts = dlt[c];
    const int dh = dparts >> 4, dw = dparts & 15;

    f32x4 oacc0[4], oacc1[4];
#pragma unroll
    for (int j = 0; j < 4; j++) { oacc0[j] = (f32x4)0.0f; oacc1[j] = (f32x4)0.0f; }
    float ssum0 = 0.0f, ssum1 = 0.0f;

#pragma unroll 1
    for (int s = 0; s < 8; ++s) {
        {
            const int npair = l >> 2;
            const int chq   = l & 3;
#pragma unroll
            for (int rr = 0; rr < 2; ++rr) {
                const int ch8 = 8 * chq + 32 * rr;
                const int2 rp = *reinterpret_cast<const int2*>(&rowoff[s * 32 + 2 * npair]);
                const ushort4* pa = reinterpret_cast<const ushort4*>(qkv + rp.x + 1024 + head * HDIM + ch8);
                const ushort4* pb = reinterpret_cast<const ushort4*>(qkv + rp.y + 1024 + head * HDIM + ch8);
                ushort4 va0 = pa[0], va1 = pa[1];
                ushort4 vb0 = pb[0], vb1 = pb[1];
                const u16* va = reinterpret_cast<const u16*>(&va0);
                const u16* vb = reinterpret_cast<const u16*>(&vb0);
#pragma unroll
                for (int e = 0; e < 4; ++e) {
                    unsigned dwo = (unsigned)va[e] | ((unsigned)vb[e] << 16);
                    *reinterpret_cast<unsigned*>(&Vt[head][ch8 + e][2 * npair]) = dwo;
                }
                const u16* va2 = reinterpret_cast<const u16*>(&va1);
                const u16* vb2 = reinterpret_cast<const u16*>(&vb1);
#pragma unroll
                for (int e = 0; e < 4; ++e) {
                    unsigned dwo = (unsigned)va2[e] | ((unsigned)vb2[e] << 16);
                    *reinterpret_cast<unsigned*>(&Vt[head][ch8 + 4 + e][2 * npair]) = dwo;
                }
            }
        }

        f32x4 sf00 = (f32x4)0.0f, sf01 = (f32x4)0.0f;
        f32x4 sf10 = (f32x4)0.0f, sf11 = (f32x4)0.0f;
        {
            const int ro = rowoff[s * 32 + c];
            const u16* kr = qkv + ro + 512 + head * HDIM;
            const bf16x8 klo = *reinterpret_cast<const bf16x8*>(kr + 8 * g);
            const bf16x8 khi = *reinterpret_cast<const bf16x8*>(kr + 32 + 8 * g);
            sf00 = __builtin_amdgcn_mfma_f32_16x16x32_bf16(klo, qlo0, sf00, 0, 0, 0);
            sf00 = __builtin_amdgcn_mfma_f32_16x16x32_bf16(khi, qhi0, sf00, 0, 0, 0);
            sf01 = __builtin_amdgcn_mfma_f32_16x16x32_bf16(klo, qlo1, sf01, 0, 0, 0);
            sf01 = __builtin_amdgcn_mfma_f32_16x16x32_bf16(khi, qhi1, sf01, 0, 0, 0);
        }
        {
            const int ro = rowoff[s * 32 + 16 + c];
            const u16* kr = qkv + ro + 512 + head * HDIM;
            const bf16x8 klo = *reinterpret_cast<const bf16x8*>(kr + 8 * g);
            const bf16x8 khi = *reinterpret_cast<const bf16x8*>(kr + 32 + 8 * g);
            sf10 = __builtin_amdgcn_mfma_f32_16x16x32_bf16(klo, qlo0, sf10, 0, 0, 0);
            sf10 = __builtin_amdgcn_mfma_f32_16x16x32_bf16(khi, qhi0, sf10, 0, 0, 0);
            sf11 = __builtin_amdgcn_mfma_f32_16x16x32_bf16(klo, qlo1, sf11, 0, 0, 0);
            sf11 = __builtin_amdgcn_mfma_f32_16x16x32_bf16(khi, qhi1, sf11, 0, 0, 0);
        }

        const int sbA  = s * 32 + 4 * g;
        const int sbB  = sbA + 16;
        const int ddA  = sbA >> 6, hhA = (sbA >> 3) & 7, wuA = sbA & 7;
        const int ddB  = sbB >> 6, hhB = (sbB >> 3) & 7, wuB = sbB & 7;
        const bool hvA = ((unsigned)(hhA - dh) < 5u);
        const bool hvB = ((unsigned)(hhB - dh) < 5u);

        unsigned pA0, pB0, pC0, pD0, pA1, pB1, pC1, pD1;
#define EXPPACK(sf, dvA_, pX, pY, SSUM, hv_, wu_) do {                          \
    const bool v_ = (dvA_) && (hv_);                                            \
    const float e0 = (v_ && (unsigned)((wu_) + 0 - dw) < 5u) ? exp2f((sf)[0]) : 0.0f; \
    const float e1 = (v_ && (unsigned)((wu_) + 1 - dw) < 5u) ? exp2f((sf)[1]) : 0.0f; \
    const float e2 = (v_ && (unsigned)((wu_) + 2 - dw) < 5u) ? exp2f((sf)[2]) : 0.0f; \
    const float e3 = (v_ && (unsigned)((wu_) + 3 - dw) < 5u) ? exp2f((sf)[3]) : 0.0f; \
    SSUM += e0 + e1 + e2 + e3;                                                  \
    pX = (unsigned)f2b(e0) | ((unsigned)f2b(e1) << 16);                         \
    pY = (unsigned)f2b(e2) | ((unsigned)f2b(e3) << 16);                         \
} while (0)

        EXPPACK(sf00, ((unsigned)(ddA - ddlt0) < 3u), pA0, pB0, ssum0, hvA, wuA);
        EXPPACK(sf10, ((unsigned)(ddB - ddlt0) < 3u), pC0, pD0, ssum0, hvB, wuB);
        EXPPACK(sf01, ((unsigned)(ddA - ddlt1) < 3u), pA1, pB1, ssum1, hvA, wuA);
        EXPPACK(sf11, ((unsigned)(ddB - ddlt1) < 3u), pC1, pD1, ssum1, hvB, wuB);
#undef EXPPACK

        asm volatile("v_permlane32_swap_b32 %0, %1" : "+v"(pA0), "+v"(pC0));
        asm volatile("v_permlane32_swap_b32 %0, %1" : "+v"(pB0), "+v"(pD0));
        asm volatile("v_permlane16_swap_b32 %0, %1" : "+v"(pA0), "+v"(pC0));
        asm volatile("v_permlane16_swap_b32 %0, %1" : "+v"(pB0), "+v"(pD0));
        asm volatile("v_permlane32_swap_b32 %0, %1" : "+v"(pA1), "+v"(pC1));
        asm volatile("v_permlane32_swap_b32 %0, %1" : "+v"(pB1), "+v"(pD1));
        asm volatile("v_permlane16_swap_b32 %0, %1" : "+v"(pA1), "+v"(pC1));
        asm volatile("v_permlane16_swap_b32 %0, %1" : "+v"(pB1), "+v"(pD1));

        {
            const bf16x8 pf0 = __builtin_bit_cast(bf16x8,
                make_int4((int)pA0, (int)pB0, (int)pC0, (int)pD0));
            const bf16x8 pf1 = __builtin_bit_cast(bf16x8,
                make_int4((int)pA1, (int)pB1, (int)pC1, (int)pD1));
#pragma unroll
            for (int j = 0; j < 4; ++j) {
                const uint2 v01 = *reinterpret_cast<const uint2*>(&Vt[head][16 * j + c][8 * g]);
                const uint2 v23 = *reinterpret_cast<const uint2*>(&Vt[head][16 * j + c][8 * g + 4]);
                const bf16x8 vfrag = __builtin_bit_cast(bf16x8,
                    make_int4((int)v01.x, (int)v01.y, (int)v23.x, (int)v23.y));
                oacc0[j] = __builtin_amdgcn_mfma_f32_16x16x32_bf16(pf0, vfrag, oacc0[j], 0, 0, 0);
                oacc1[j] = __builtin_amdgcn_mfma_f32_16x16x32_bf16(pf1, vfrag, oacc1[j], 0, 0, 0);
            }
        }
    }

    ssum0 += __shfl_xor(ssum0, 16);
    ssum0 += __shfl_xor(ssum0, 32);
    ssum1 += __shfl_xor(ssum1, 16);
    ssum1 += __shfl_xor(ssum1, 32);
    if (l < 16) {
        ssum_lds[head][0][c] = ssum0;
        ssum_lds[head][1][c] = ssum1;
    }
    const f32x4 sums40 = *reinterpret_cast<const f32x4*>(&ssum_lds[head][0][4 * g]);
    const f32x4 sums41 = *reinterpret_cast<const f32x4*>(&ssum_lds[head][1][4 * g]);

    const int obase = (h0 + g) * WWW + w0;
    const int orow0 = (2 * d0)     * (HHH * WWW) + obase;
    const int orow1 = (2 * d0 + 1) * (HHH * WWW) + obase;
#pragma unroll
    for (int r = 0; r < 4; ++r) {
        const float inv0 = 1.0f / sums40[r];
        const float inv1 = 1.0f / sums41[r];
        u16* base0 = attnc + (size_t)(orow0 + r) * 512 + head * HDIM;
        u16* base1 = attnc + (size_t)(orow1 + r) * 512 + head * HDIM;
#pragma unroll
        for (int j = 0; j < 4; ++j) {
            base0[16 * j + c] = f2b(oacc0[j][r] * inv0);
            base1[16 * j + c] = f2b(oacc1[j][r] * inv1);
        }
    }
}

// ---------------------------------------------------------------------------
extern "C" void kernel_launch(void* const* d_in, const int* in_sizes, int n_in,
                              void* d_out, int out_size, void* d_ws, size_t ws_size,
                              hipStream_t stream)
{
    const float* x      = (const float*)d_in[0];
    const float* w_qkv  = (const float*)d_in[1];
    const float* b_qkv  = (const float*)d_in[2];
    const float* w_proj = (const float*)d_in[3];
    const float* b_proj = (const float*)d_in[4];
    float* out = (float*)d_out;

    u16* qkvb   = (u16*)d_ws;                         // [27648][1536]
    u16* attnc  = qkvb  + (size_t)NPOS * 1536;        // [27648][512] bf16
    u16* xb     = attnc + (size_t)NPOS * 512;         // [27648][512]
    u16* wqkvT  = xb    + (size_t)NPOS * 512;         // [1536][512]
    u16* wprojT = wqkvT + (size_t)1536 * 512;         // [512][512]

    // 0) all converts in one launch
    cvt_all<<<17920, 256, 0, stream>>>(x, w_qkv, w_proj, xb, wqkvT, wprojT);

    // 1) qkv = x @ w_qkv + b_qkv (q pre-scaled); grid 108*12 = 1296 = 8*162
    gemm_bf16_mfma<<<(NPOS / 256) * (1536 / 128), 512, 0, stream>>>(
        xb, 512, wqkvT, 512, b_qkv, 512, qkvb, 1536, 1, 1536 / 128);

    // 2) attention -> bf16 [NPOS][512]; 864 blocks = 8 x 108 (2x4x4 tiles)
    na3d_mfma<<<NPOS / 32, 512, 0, stream>>>(qkvb, attnc);

    // 3) out = attn @ w_proj + b_proj ; grid 108*4 = 432 = 8*54
    gemm_bf16_mfma<<<(NPOS / 256) * (512 / 128), 512, 0, stream>>>(
        attnc, 512, wprojT, 512, b_proj, 512, out, 512, 0, 512 / 128);
}